// Round 6
// baseline (164.861 us; speedup 1.0000x reference)
//
#include <hip/hip_runtime.h>

// DetectionLoss: NB=3, C=20, S=7, D=35, B=8192 -> 401408 cells, ~112 MB read.
// R6: copy-kernel-shaped loads (consecutive lanes -> consecutive float4,
// plain dwordx4 to REGISTERS — the only pattern measured at 6.3 TB/s),
// register->LDS->register transpose, persistent single-wave blocks, no
// barriers. Evidence: LDS-DMA staging plateaued at 3.3 TB/s regardless of
// occupancy (R3=8 waves/CU, R4=4 waves/CU, same 34us); strided direct loads
// hit 3 TB/s + 1.4x overfetch (R5). Plain contiguous loads pipeline (m13).
// Pipeline per wave: load tile t+1 into r[18] -> compute tile t from LDS ->
// ds_write r[] (auto per-register vmcnt waits). LDS in-order per wave makes
// single-buffering safe. 8 waves/CU x 18KB in flight = 144KB >> 9KB needed.

#define NBOX 3
#define NCLS 20
#define SDIM 7
#define DCH  35
#define TILE_F4 560            // float4 per tensor per 64-cell tile
#define FLAT_F4 (2 * TILE_F4)  // 1120
#define LDS_F4  1152           // + 32 pad (18*64), 18432 B -> 8 waves/CU

__global__ __launch_bounds__(64) void detloss_kernel(
    const float* __restrict__ out_g, const float* __restrict__ tgt_g,
    float* __restrict__ partials, int n_tiles, float inv_nB)
{
    __shared__ float4 s_buf[LDS_F4];    // [0,560)=out, [560,1120)=tgt, rest pad

    const int lane = threadIdx.x;       // one wave per block
    const int wid  = blockIdx.x;
    const int nwv  = gridDim.x;

    float4 r[18];
    float lane_sum = 0.0f;

    // ---- 18 contiguous dwordx4 loads (copy-kernel pattern) ----
    auto load_tile = [&](int tile) {
        const float4* go = (const float4*)out_g + (long long)tile * TILE_F4;
        const float4* gt = (const float4*)tgt_g + (long long)tile * TILE_F4;
        #pragma unroll
        for (int j = 0; j < 18; ++j) {
            int k = j * 64 + lane;
            k = (k > FLAT_F4 - 1) ? (FLAT_F4 - 1) : k;   // clamp pad lanes (j=17,lane>=32)
            r[j] = (k < TILE_F4) ? go[k] : gt[k - TILE_F4];
        }
    };

    auto store_tile = [&]() {           // compiler inserts per-register vmcnt(N)
        #pragma unroll
        for (int j = 0; j < 18; ++j)
            s_buf[j * 64 + lane] = r[j];
    };

    auto compute = [&]() {
        const float* sf = (const float*)s_buf;
        const float* o  = sf + lane * DCH;                 // packed 140B cells
        const float* g  = sf + 4 * TILE_F4 + lane * DCH;   // tgt section

        const float tx  = g[0] / 7.0f, ty = g[1] / 7.0f;
        const float thw = 0.5f * g[2], thh = 0.5f * g[3];
        const float tx1 = tx - thw, ty1 = ty - thh;
        const float tx2 = tx + thw, ty2 = ty + thh;
        const float a2  = (tx2 - tx1) * (ty2 - ty1);

        const float conf_t = g[4];
        const float obj    = (conf_t == 1.0f) ? 1.0f : 0.0f;
        const float noobj  = (conf_t == 0.0f) ? 1.0f : 0.0f;

        float biou = -__builtin_inff();  // strict > => first-index-wins (matches argmax)
        float conf_sq = 0.0f;
        float bo0 = 0.f, bo1 = 0.f, bo2 = 0.f, bo3 = 0.f, bo4 = 0.f;
        float bg0 = 0.f, bg1 = 0.f, bg2 = 0.f, bg3 = 0.f;

        #pragma unroll
        for (int i = 0; i < NBOX; ++i) {
            const float px  = o[5*i]   / 7.0f;
            const float py  = o[5*i+1] / 7.0f;
            const float phw = 0.5f * o[5*i+2];
            const float phh = 0.5f * o[5*i+3];
            const float px1 = px - phw, py1 = py - phh;
            const float px2 = px + phw, py2 = py + phh;

            const float ltx = fmaxf(px1, tx1), lty = fmaxf(py1, ty1);
            const float rbx = fminf(px2, tx2), rby = fminf(py2, ty2);
            const float w = fmaxf(rbx - ltx, 0.0f);
            const float h = fmaxf(rby - lty, 0.0f);
            const float inter = w * h;
            const float a1 = (px2 - px1) * (py2 - py1);
            const float iou = inter / (a1 + a2 - inter);

            const bool better = iou > biou;
            biou = better ? iou      : biou;
            bo0  = better ? o[5*i]   : bo0;
            bo1  = better ? o[5*i+1] : bo1;
            bo2  = better ? o[5*i+2] : bo2;
            bo3  = better ? o[5*i+3] : bo3;
            bo4  = better ? o[5*i+4] : bo4;
            bg0  = better ? g[5*i]   : bg0;
            bg1  = better ? g[5*i+1] : bg1;
            bg2  = better ? g[5*i+2] : bg2;
            bg3  = better ? g[5*i+3] : bg3;

            const float dc = o[5*i+4] - g[5*i+4];
            conf_sq += dc * dc;
        }

        float loss = 0.5f * noobj * conf_sq;

        const float dx = bo0 - bg0;
        const float dy = bo1 - bg1;
        const float xyl = dx*dx + dy*dy;
        const float dw = sqrtf(bo2) - sqrtf(bg2);
        const float dh = sqrtf(bo3) - sqrtf(bg3);
        const float whl = dw*dw + dh*dh;
        const float dcf = bo4 - biou;
        const float contain = dcf * dcf;

        float cls = 0.0f;
        #pragma unroll
        for (int c = 0; c < NCLS; ++c) {
            const float d = o[5*NBOX + c] - g[5*NBOX + c];
            cls += d * d;
        }

        lane_sum += loss + obj * (5.0f * (xyl + whl) + contain + cls);
    };

    // ---- software pipeline: load(t+1) ahead of compute(t), no barriers ----
    if (wid < n_tiles) {
        load_tile(wid);
        store_tile();
        for (int nxt = wid + nwv; nxt < n_tiles; nxt += nwv) {
            load_tile(nxt);     // 18 loads in flight across compute below
            compute();          // reads LDS (in-order per wave vs writes after)
            store_tile();
        }
        compute();
    }

    // ---- wave reduce -> one partial per wave ----
    float v = lane_sum * inv_nB;
    #pragma unroll
    for (int off = 32; off > 0; off >>= 1)
        v += __shfl_down(v, off);
    if (lane == 0) partials[wid] = v;
}

__global__ __launch_bounds__(1024) void reduce_kernel(
    const float* __restrict__ partials, float* __restrict__ out, int n)
{
    __shared__ float s[1024 / 64];
    float v = 0.0f;
    for (int i = threadIdx.x; i < n; i += 1024) v += partials[i];
    #pragma unroll
    for (int off = 32; off > 0; off >>= 1)
        v += __shfl_down(v, off);
    if ((threadIdx.x & 63) == 0) s[threadIdx.x >> 6] = v;
    __syncthreads();
    if (threadIdx.x == 0) {
        float t = 0.0f;
        #pragma unroll
        for (int w = 0; w < 1024 / 64; ++w) t += s[w];
        out[0] = t;
    }
}

extern "C" void kernel_launch(void* const* d_in, const int* in_sizes, int n_in,
                              void* d_out, int out_size, void* d_ws, size_t ws_size,
                              hipStream_t stream) {
    const float* out_p = (const float*)d_in[0];
    const float* tgt_p = (const float*)d_in[1];
    float* res  = (float*)d_out;
    float* part = (float*)d_ws;

    const int n_cells = in_sizes[0] / DCH;            // 401408
    const int nB = n_cells / (SDIM * SDIM);           // 8192
    const float inv_nB = 1.0f / (float)nB;
    const int n_tiles = n_cells / 64;                 // 6272 (exact)

    const int nblocks = 2048;                         // 8 single-wave blocks/CU (LDS-capped)
    hipLaunchKernelGGL(detloss_kernel, dim3(nblocks), dim3(64), 0, stream,
                       out_p, tgt_p, part, n_tiles, inv_nB);
    hipLaunchKernelGGL(reduce_kernel, dim3(1), dim3(1024), 0, stream,
                       part, res, nblocks);
}